// Round 20
// baseline (105.953 us; speedup 1.0000x reference)
//
#include <hip/hip_runtime.h>
#include <hip/hip_bf16.h>

#define NB 64
#define NC 256
#define NL 2048
#define NH 8
#define KW 3
#define LP (NL - KW + 1)  // 2046
#define NCHUNK 4
#define CPC 64  // channels per chunk = two 32-channel halves merged in-block

typedef float v4f __attribute__((ext_vector_type(4)));

// monotonic float->uint key: order(u) == order(x)
__device__ __forceinline__ unsigned fkey(float x) {
  unsigned b = __float_as_uint(x);
  return (b & 0x80000000u) ? ~b : (b | 0x80000000u);
}

// Kernel 1 (R8 inner loop verbatim, 512-thread half-merge): threads 0-255
// run the proven 32-channel conv body on channels [cc*64, +32), threads
// 256-511 on [+32, +64); one LDS pass sums the halves -> ONE part chunk.
// part shrinks 32->16 MB (the NCHUNK traffic slope measured ~6-8us/32MB).
// Grid (2, NB, 4) = 512 blocks x 8 waves = 16 waves/CU (same as R8).
__global__ __launch_bounds__(512) void conv_partial(
    const float* __restrict__ src, const float* __restrict__ conv_w,
    float* __restrict__ part) {
  const int t = threadIdx.x;   // 0..511
  const int tt = t & 255;      // position within half
  const int half = t >> 8;     // 0 or 1
  const int lane = t & 63;     // == tt & 63
  const int l0 = blockIdx.x * 1024 + tt * 4;
  const int b = blockIdx.y;
  const int cc = blockIdx.z;   // 0..3
  const int c0 = cc * CPC + half * 32;

  __shared__ float red[NH * 1024];  // 32 KB half-0 accumulator staging

  float acc[NH][4];
#pragma unroll
  for (int h = 0; h < NH; ++h)
#pragma unroll
    for (int j = 0; j < 4; ++j) acc[h][j] = 0.f;

  const float* sp = src + ((size_t)b * NC + c0) * NL + l0;
  const bool tail = (lane == 63) && (l0 + 5 < NL);
#pragma unroll 2
  for (int c = 0; c < 32; ++c) {
    v4f v = *(const v4f*)sp;
    float e0 = 0.f, e1 = 0.f;
    if (tail) { e0 = sp[4]; e1 = sp[5]; }
    sp += NL;
    float n0 = __shfl_down(v.x, 1);
    float n1 = __shfl_down(v.y, 1);
    if (lane == 63) { n0 = e0; n1 = e1; }
    float s0 = v.x, s1 = v.y, s2 = v.z, s3 = v.w, s4 = n0, s5 = n1;
#pragma unroll
    for (int h = 0; h < NH; ++h) {
      const float* w = conv_w + (h * NC + c0 + c) * KW;  // uniform -> s_load
      const float w0 = w[0], w1 = w[1], w2 = w[2];
      acc[h][0] = fmaf(s0, w0, fmaf(s1, w1, fmaf(s2, w2, acc[h][0])));
      acc[h][1] = fmaf(s1, w0, fmaf(s2, w1, fmaf(s3, w2, acc[h][1])));
      acc[h][2] = fmaf(s2, w0, fmaf(s3, w1, fmaf(s4, w2, acc[h][2])));
      acc[h][3] = fmaf(s3, w0, fmaf(s4, w1, fmaf(s5, w2, acc[h][3])));
    }
  }
  // half 0 stages its accumulators; half 1 adds and writes the merged chunk
  if (half == 0) {
#pragma unroll
    for (int h = 0; h < NH; ++h)
      *(v4f*)&red[h * 1024 + tt * 4] = *(v4f*)acc[h];
  }
  __syncthreads();
  if (half == 1) {
#pragma unroll
    for (int h = 0; h < NH; ++h) {
      v4f s = *(v4f*)acc[h] + *(const v4f*)&red[h * 1024 + tt * 4];
      float* pr = part + ((size_t)(b * NH + h) * NCHUNK + cc) * NL + l0;
      if (l0 + 3 < LP) {
        *(v4f*)pr = s;
      } else {
#pragma unroll
        for (int j = 0; j < 4; ++j)
          if (l0 + j < LP) pr[j] = s[j];
      }
    }
  }
}

// Kernel 2 (R18-verbatim machinery, 4 partial streams): raw-key radix,
// BN never materialized (monotone affine -> rank-equivalent; key flipped
// if gamma<0); one fused load+stats+histogram sweep; candidate compaction;
// tie counts derived from radix state.
__global__ __launch_bounds__(256) void select_block(
    const float* __restrict__ part, float* __restrict__ xi,
    const float* __restrict__ conv_b, const float* __restrict__ bn_gamma,
    const float* __restrict__ bn_beta, const float* __restrict__ comb_w,
    const int* __restrict__ kptr) {
  const int t = threadIdx.x;
  const int lane = t & 63, wid = t >> 6;
  const int bh = blockIdx.x;
  const int h = bh & (NH - 1);
  __shared__ __align__(16) float xs[NL];       // raw values (pad tail unused)
  __shared__ __align__(16) float smp[NL + 4];  // doubles as cand[] in radix
  __shared__ int hist[256];
  __shared__ float rs[8];
  __shared__ float fbc[2];
  __shared__ int ibc[4];
  __shared__ int cnt;
  float* cand = smp;

  const float gma = bn_gamma[h];
  const unsigned kxor = (gma < 0.f) ? 0xFFFFFFFFu : 0u;  // key flip for sc<0
#define KEY(x) (fkey(x) ^ kxor)

  hist[t] = 0;
  __syncthreads();  // all histogram slots zeroed before any atomics

  // phase A: ONE sweep = v4f 4-stream sum (+bias) -> xs, raw stats,
  // raw-key top-byte histogram.
  const float cb = conv_b[h];
  const v4f* p0v = (const v4f*)(part + (size_t)bh * NCHUNK * NL);
  const v4f cbv = {cb, cb, cb, cb};
  float s1 = 0.f, s2 = 0.f;
#pragma unroll
  for (int half = 0; half < 2; ++half) {
    const int i0 = half * 1024 + t * 4;  // 0..2044, %4==0
    const int j = i0 >> 2;
    v4f a0 = p0v[j]        + p0v[j + 512];
    v4f a1 = p0v[j + 1024] + p0v[j + 1536];
    v4f v = (a0 + a1) + cbv;
    *(v4f*)&xs[i0] = v;  // elements >= LP never read by keyed sweeps
    if (i0 + 3 < LP) {
      s1 += (v.x + v.y) + (v.z + v.w);
      s2 += (v.x * v.x + v.y * v.y) + (v.z * v.z + v.w * v.w);
      atomicAdd(&hist[KEY(v.x) >> 24], 1);
      atomicAdd(&hist[KEY(v.y) >> 24], 1);
      atomicAdd(&hist[KEY(v.z) >> 24], 1);
      atomicAdd(&hist[KEY(v.w) >> 24], 1);
    } else {  // i0 == 2044: only 2044,2045 are real
      s1 += v.x + v.y;
      s2 += v.x * v.x + v.y * v.y;
      atomicAdd(&hist[KEY(v.x) >> 24], 1);
      atomicAdd(&hist[KEY(v.y) >> 24], 1);
    }
  }
#pragma unroll
  for (int off = 32; off > 0; off >>= 1) {
    s1 += __shfl_down(s1, off);
    s2 += __shfl_down(s2, off);
  }
  if (lane == 0) { rs[wid] = s1; rs[wid + 4] = s2; }
  __syncthreads();  // hist + rs complete

  int kk = kptr[0];
#define RADIX_SCAN()                                                          \
  if (t < 64) {                                                               \
    const int h0 = hist[t * 4 + 0], h1 = hist[t * 4 + 1];                     \
    const int h2 = hist[t * 4 + 2], h3 = hist[t * 4 + 3];                     \
    const int g = h0 + h1 + h2 + h3;                                          \
    int sfx = g;                                                              \
    _Pragma("unroll")                                                         \
    for (int off = 1; off < 64; off <<= 1) {                                  \
      int o = __shfl(sfx, (t + off) & 63);                                    \
      if (t + off < 64) sfx += o;                                             \
    }                                                                         \
    const int A = sfx - g;                                                    \
    const int q3 = A + h3, q2 = q3 + h2, q1 = q2 + h1, q0 = q1 + h0;          \
    int mybin = -1, mykk = 0, myct = 0;                                       \
    if (q0 >= kk && q0 - h0 < kk) { mybin = t * 4 + 0; mykk = kk - (q0 - h0); myct = h0; } \
    if (q1 >= kk && q1 - h1 < kk) { mybin = t * 4 + 1; mykk = kk - (q1 - h1); myct = h1; } \
    if (q2 >= kk && q2 - h2 < kk) { mybin = t * 4 + 2; mykk = kk - (q2 - h2); myct = h2; } \
    if (q3 >= kk && q3 - h3 < kk) { mybin = t * 4 + 3; mykk = kk - (q3 - h3); myct = h3; } \
    if (mybin >= 0) { ibc[0] = mybin; ibc[1] = mykk; ibc[3] = myct; }         \
  }

  // stats finalize + pass-0 radix scan share one barrier section
  if (t == 0) {
    float S = rs[0] + rs[1] + rs[2] + rs[3];
    float Q = rs[4] + rs[5] + rs[6] + rs[7];
    float mu = S / (float)LP;
    float var = Q / (float)LP - mu * mu;
    float inv = rsqrtf(var + 1e-5f);
    float sc = gma * inv;
    fbc[0] = sc;
    fbc[1] = bn_beta[h] - mu * sc;
    cnt = 0;
  }
  RADIX_SCAN();
  __syncthreads();  // ibc, fbc, cnt ready

  unsigned prefix = ((unsigned)ibc[0]) << 24;
  unsigned pm = 0xFF000000u;
  kk = ibc[1];
  const unsigned b0 = (unsigned)ibc[0];

  // compact the selected top-byte bin into cand[] (order-independent result)
  for (int i = t; i < LP; i += 256) {
    float x = xs[i];
    if ((KEY(x) >> 24) == b0) {
      int p = atomicAdd(&cnt, 1);
      cand[p] = x;
    }
  }
  __syncthreads();
  const int n1 = cnt;

  // passes 1..3 over the small candidate list (raw keys)
  for (int pass = 1; pass < 4; ++pass) {
    const int shift = 24 - 8 * pass;
    hist[t] = 0;
    __syncthreads();
    for (int i = t; i < n1; i += 256) {
      unsigned u = KEY(cand[i]);
      if ((u & pm) == prefix) atomicAdd(&hist[(u >> shift) & 255], 1);
    }
    __syncthreads();
    RADIX_SCAN();
    __syncthreads();
    prefix |= ((unsigned)ibc[0]) << shift;
    pm |= 255u << shift;
    kk = ibc[1];
  }
  const unsigned T = prefix;
  const int need_eq = kk;      // # needed among keys == T (derived)
  const int ceq = ibc[3];      // # keys == T (final-pass bin count)
  const bool tie = (ceq != need_eq);

  // mask + BN + sigmoid -> smp (fully overwrites the cand alias)
  const float sc = fbc[0], sh = fbc[1];
  for (int i = t; i < LP; i += 256) {
    float x = xs[i];
    unsigned u = KEY(x);
    bool sel = tie ? (u > T) : (u >= T);
    smp[i + 2] = sel ? 1.f / (1.f + __expf(-fmaf(x, sc, sh))) : 0.f;
  }
  if (t < 2) smp[t] = 0.f;
  if (t < 4) smp[NL + t] = 0.f;  // covers smp[2048..2051] for v4f reads
  __syncthreads();
  if (tie && t == 0) {  // rare: stable lowest-index-first like lax.top_k
    int taken = 0;
    for (int i = 0; i < LP && taken < need_eq; ++i) {
      float x = xs[i];
      if (KEY(x) == T) {
        smp[i + 2] = 1.f / (1.f + __expf(-fmaf(x, sc, sh)));
        ++taken;
      }
    }
  }
  __syncthreads();

  // 3-tap box sum, v4f output (in-register shifts from two aligned LDS v4f)
  const float cw = comb_w[h] * (1.0f / (float)KW);
  float* row = xi + (size_t)bh * NL;
#pragma unroll
  for (int q = 0; q < 2; ++q) {
    const int l = q * 1024 + t * 4;
    v4f a = *(const v4f*)&smp[l];
    v4f bsh = *(const v4f*)&smp[l + 4];
    v4f u1 = {a.y, a.z, a.w, bsh.x};
    v4f u2 = {a.z, a.w, bsh.x, bsh.y};
    v4f r = (a + u1 + u2);
    r.x *= cw; r.y *= cw; r.z *= cw; r.w *= cw;
    *(v4f*)&row[l] = r;
  }
#undef KEY
#undef RADIX_SCAN
}

// Kernel 3 (R18-verbatim): each thread owns one (b,l4) pair, computes the
// 8-head gate sum once, reuses it across 16 channels of coalesced
// src-load + plain store. ~45us, near the 272MB mixed-stream ceiling.
__global__ __launch_bounds__(256) void scale_gate(
    const float* __restrict__ src, const float* __restrict__ xi,
    const float* __restrict__ comb_b, float* __restrict__ out) {
  const int t = threadIdx.x;
  const int cchunk = blockIdx.x >> 7;               // 0..15, 16 channels each
  const int pairidx = (blockIdx.x & 127) * 256 + t; // 0..32767
  const int b = pairidx >> 9;                       // NL/4 = 512 l4 per b
  const int l4 = pairidx & 511;
  const float cb = comb_b[0];

  const v4f* xp = (const v4f*)(xi + (size_t)b * NH * NL) + l4;
  v4f g = xp[0];
#pragma unroll
  for (int h = 1; h < NH; ++h) g += xp[(size_t)h * (NL / 4)];

  const int c0 = cchunk * (NC / 16);
  const v4f* sp = (const v4f*)src + ((size_t)b * NC + c0) * (NL / 4) + l4;
  v4f* op = (v4f*)out + ((size_t)b * NC + c0) * (NL / 4) + l4;
#pragma unroll 4
  for (int c = 0; c < NC / 16; ++c) {
    v4f sv = sp[(size_t)c * (NL / 4)];
    v4f ov;
    ov.x = fmaf(sv.x, g.x, cb);
    ov.y = fmaf(sv.y, g.y, cb);
    ov.z = fmaf(sv.z, g.z, cb);
    ov.w = fmaf(sv.w, g.w, cb);
    op[(size_t)c * (NL / 4)] = ov;
  }
}

extern "C" void kernel_launch(void* const* d_in, const int* in_sizes, int n_in,
                              void* d_out, int out_size, void* d_ws, size_t ws_size,
                              hipStream_t stream) {
  const float* src = (const float*)d_in[0];
  const float* conv_w = (const float*)d_in[1];
  const float* conv_b = (const float*)d_in[2];
  const float* bn_gamma = (const float*)d_in[3];
  const float* bn_beta = (const float*)d_in[4];
  const float* comb_w = (const float*)d_in[5];
  const float* comb_b = (const float*)d_in[6];
  const int* kptr = (const int*)d_in[7];
  float* out = (float*)d_out;

  float* xi = (float*)d_ws;  // NB*NH*NL floats (4 MB)
  float* part = out;         // 16 MB scratch inside d_out: consumed by
                             // select_block, then overwritten by scale_gate

  conv_partial<<<dim3(2, NB, NCHUNK), 512, 0, stream>>>(src, conv_w, part);
  select_block<<<NB * NH, 256, 0, stream>>>(part, xi, conv_b, bn_gamma,
                                            bn_beta, comb_w, kptr);
  scale_gate<<<2048, 256, 0, stream>>>(src, xi, comb_b, out);
}

// Round 21
// 102.258 us; speedup vs baseline: 1.0361x; 1.0361x over previous
//
#include <hip/hip_runtime.h>
#include <hip/hip_bf16.h>

#define NB 64
#define NC 256
#define NL 2048
#define NH 8
#define KW 3
#define LP (NL - KW + 1)  // 2046
#define NCHUNK 4
#define CPC 64  // channels per chunk = two 32-channel halves merged in-block

typedef float v4f __attribute__((ext_vector_type(4)));

// monotonic float->uint key: order(u) == order(x)
__device__ __forceinline__ unsigned fkey(float x) {
  unsigned b = __float_as_uint(x);
  return (b & 0x80000000u) ? ~b : (b | 0x80000000u);
}

// Kernel 1 (R8 inner loop verbatim, 512-thread half-merge): threads 0-255
// run the proven 32-channel conv body on channels [cc*64, +32), threads
// 256-511 on [+32, +64); one LDS pass sums the halves -> ONE part chunk.
// part shrinks 32->16 MB (the NCHUNK traffic slope measured ~6-8us/32MB).
// Grid (2, NB, 4) = 512 blocks x 8 waves = 16 waves/CU (same as R8).
__global__ __launch_bounds__(512) void conv_partial(
    const float* __restrict__ src, const float* __restrict__ conv_w,
    float* __restrict__ part) {
  const int t = threadIdx.x;   // 0..511
  const int tt = t & 255;      // position within half
  const int half = t >> 8;     // 0 or 1
  const int lane = t & 63;     // == tt & 63
  const int l0 = blockIdx.x * 1024 + tt * 4;
  const int b = blockIdx.y;
  const int cc = blockIdx.z;   // 0..3
  const int c0 = cc * CPC + half * 32;

  __shared__ float red[NH * 1024];  // 32 KB half-0 accumulator staging

  float acc[NH][4];
#pragma unroll
  for (int h = 0; h < NH; ++h)
#pragma unroll
    for (int j = 0; j < 4; ++j) acc[h][j] = 0.f;

  const float* sp = src + ((size_t)b * NC + c0) * NL + l0;
  const bool tail = (lane == 63) && (l0 + 5 < NL);
#pragma unroll 2
  for (int c = 0; c < 32; ++c) {
    v4f v = *(const v4f*)sp;
    float e0 = 0.f, e1 = 0.f;
    if (tail) { e0 = sp[4]; e1 = sp[5]; }
    sp += NL;
    float n0 = __shfl_down(v.x, 1);
    float n1 = __shfl_down(v.y, 1);
    if (lane == 63) { n0 = e0; n1 = e1; }
    float s0 = v.x, s1 = v.y, s2 = v.z, s3 = v.w, s4 = n0, s5 = n1;
#pragma unroll
    for (int h = 0; h < NH; ++h) {
      const float* w = conv_w + (h * NC + c0 + c) * KW;  // uniform -> s_load
      const float w0 = w[0], w1 = w[1], w2 = w[2];
      acc[h][0] = fmaf(s0, w0, fmaf(s1, w1, fmaf(s2, w2, acc[h][0])));
      acc[h][1] = fmaf(s1, w0, fmaf(s2, w1, fmaf(s3, w2, acc[h][1])));
      acc[h][2] = fmaf(s2, w0, fmaf(s3, w1, fmaf(s4, w2, acc[h][2])));
      acc[h][3] = fmaf(s3, w0, fmaf(s4, w1, fmaf(s5, w2, acc[h][3])));
    }
  }
  // half 0 stages its accumulators; half 1 adds and writes the merged chunk
  if (half == 0) {
#pragma unroll
    for (int h = 0; h < NH; ++h)
      *(v4f*)&red[h * 1024 + tt * 4] = *(v4f*)acc[h];
  }
  __syncthreads();
  if (half == 1) {
#pragma unroll
    for (int h = 0; h < NH; ++h) {
      v4f s = *(v4f*)acc[h] + *(const v4f*)&red[h * 1024 + tt * 4];
      float* pr = part + ((size_t)(b * NH + h) * NCHUNK + cc) * NL + l0;
      if (l0 + 3 < LP) {
        *(v4f*)pr = s;
      } else {
#pragma unroll
        for (int j = 0; j < 4; ++j)
          if (l0 + j < LP) pr[j] = s[j];
      }
    }
  }
}

// Kernel 2 (R18-verbatim machinery, 4 partial streams): raw-key radix,
// BN never materialized (monotone affine -> rank-equivalent; key flipped
// if gamma<0); one fused load+stats+histogram sweep; candidate compaction;
// tie counts derived from radix state.
__global__ __launch_bounds__(256) void select_block(
    const float* __restrict__ part, float* __restrict__ xi,
    const float* __restrict__ conv_b, const float* __restrict__ bn_gamma,
    const float* __restrict__ bn_beta, const float* __restrict__ comb_w,
    const int* __restrict__ kptr) {
  const int t = threadIdx.x;
  const int lane = t & 63, wid = t >> 6;
  const int bh = blockIdx.x;
  const int h = bh & (NH - 1);
  __shared__ __align__(16) float xs[NL];       // raw values (pad tail unused)
  __shared__ __align__(16) float smp[NL + 4];  // doubles as cand[] in radix
  __shared__ int hist[256];
  __shared__ float rs[8];
  __shared__ float fbc[2];
  __shared__ int ibc[4];
  __shared__ int cnt;
  float* cand = smp;

  const float gma = bn_gamma[h];
  const unsigned kxor = (gma < 0.f) ? 0xFFFFFFFFu : 0u;  // key flip for sc<0
#define KEY(x) (fkey(x) ^ kxor)

  hist[t] = 0;
  __syncthreads();  // all histogram slots zeroed before any atomics

  // phase A: ONE sweep = v4f 4-stream sum (+bias) -> xs, raw stats,
  // raw-key top-byte histogram.
  const float cb = conv_b[h];
  const v4f* p0v = (const v4f*)(part + (size_t)bh * NCHUNK * NL);
  const v4f cbv = {cb, cb, cb, cb};
  float s1 = 0.f, s2 = 0.f;
#pragma unroll
  for (int half = 0; half < 2; ++half) {
    const int i0 = half * 1024 + t * 4;  // 0..2044, %4==0
    const int j = i0 >> 2;
    v4f a0 = p0v[j]        + p0v[j + 512];
    v4f a1 = p0v[j + 1024] + p0v[j + 1536];
    v4f v = (a0 + a1) + cbv;
    *(v4f*)&xs[i0] = v;  // elements >= LP never read by keyed sweeps
    if (i0 + 3 < LP) {
      s1 += (v.x + v.y) + (v.z + v.w);
      s2 += (v.x * v.x + v.y * v.y) + (v.z * v.z + v.w * v.w);
      atomicAdd(&hist[KEY(v.x) >> 24], 1);
      atomicAdd(&hist[KEY(v.y) >> 24], 1);
      atomicAdd(&hist[KEY(v.z) >> 24], 1);
      atomicAdd(&hist[KEY(v.w) >> 24], 1);
    } else {  // i0 == 2044: only 2044,2045 are real
      s1 += v.x + v.y;
      s2 += v.x * v.x + v.y * v.y;
      atomicAdd(&hist[KEY(v.x) >> 24], 1);
      atomicAdd(&hist[KEY(v.y) >> 24], 1);
    }
  }
#pragma unroll
  for (int off = 32; off > 0; off >>= 1) {
    s1 += __shfl_down(s1, off);
    s2 += __shfl_down(s2, off);
  }
  if (lane == 0) { rs[wid] = s1; rs[wid + 4] = s2; }
  __syncthreads();  // hist + rs complete

  int kk = kptr[0];
#define RADIX_SCAN()                                                          \
  if (t < 64) {                                                               \
    const int h0 = hist[t * 4 + 0], h1 = hist[t * 4 + 1];                     \
    const int h2 = hist[t * 4 + 2], h3 = hist[t * 4 + 3];                     \
    const int g = h0 + h1 + h2 + h3;                                          \
    int sfx = g;                                                              \
    _Pragma("unroll")                                                         \
    for (int off = 1; off < 64; off <<= 1) {                                  \
      int o = __shfl(sfx, (t + off) & 63);                                    \
      if (t + off < 64) sfx += o;                                             \
    }                                                                         \
    const int A = sfx - g;                                                    \
    const int q3 = A + h3, q2 = q3 + h2, q1 = q2 + h1, q0 = q1 + h0;          \
    int mybin = -1, mykk = 0, myct = 0;                                       \
    if (q0 >= kk && q0 - h0 < kk) { mybin = t * 4 + 0; mykk = kk - (q0 - h0); myct = h0; } \
    if (q1 >= kk && q1 - h1 < kk) { mybin = t * 4 + 1; mykk = kk - (q1 - h1); myct = h1; } \
    if (q2 >= kk && q2 - h2 < kk) { mybin = t * 4 + 2; mykk = kk - (q2 - h2); myct = h2; } \
    if (q3 >= kk && q3 - h3 < kk) { mybin = t * 4 + 3; mykk = kk - (q3 - h3); myct = h3; } \
    if (mybin >= 0) { ibc[0] = mybin; ibc[1] = mykk; ibc[3] = myct; }         \
  }

  // stats finalize + pass-0 radix scan share one barrier section
  if (t == 0) {
    float S = rs[0] + rs[1] + rs[2] + rs[3];
    float Q = rs[4] + rs[5] + rs[6] + rs[7];
    float mu = S / (float)LP;
    float var = Q / (float)LP - mu * mu;
    float inv = rsqrtf(var + 1e-5f);
    float sc = gma * inv;
    fbc[0] = sc;
    fbc[1] = bn_beta[h] - mu * sc;
    cnt = 0;
  }
  RADIX_SCAN();
  __syncthreads();  // ibc, fbc, cnt ready

  unsigned prefix = ((unsigned)ibc[0]) << 24;
  unsigned pm = 0xFF000000u;
  kk = ibc[1];
  const unsigned b0 = (unsigned)ibc[0];

  // compact the selected top-byte bin into cand[] (order-independent result)
  for (int i = t; i < LP; i += 256) {
    float x = xs[i];
    if ((KEY(x) >> 24) == b0) {
      int p = atomicAdd(&cnt, 1);
      cand[p] = x;
    }
  }
  __syncthreads();
  const int n1 = cnt;

  // passes 1..3 over the small candidate list (raw keys)
  for (int pass = 1; pass < 4; ++pass) {
    const int shift = 24 - 8 * pass;
    hist[t] = 0;
    __syncthreads();
    for (int i = t; i < n1; i += 256) {
      unsigned u = KEY(cand[i]);
      if ((u & pm) == prefix) atomicAdd(&hist[(u >> shift) & 255], 1);
    }
    __syncthreads();
    RADIX_SCAN();
    __syncthreads();
    prefix |= ((unsigned)ibc[0]) << shift;
    pm |= 255u << shift;
    kk = ibc[1];
  }
  const unsigned T = prefix;
  const int need_eq = kk;      // # needed among keys == T (derived)
  const int ceq = ibc[3];      // # keys == T (final-pass bin count)
  const bool tie = (ceq != need_eq);

  // mask + BN + sigmoid -> smp (fully overwrites the cand alias)
  const float sc = fbc[0], sh = fbc[1];
  for (int i = t; i < LP; i += 256) {
    float x = xs[i];
    unsigned u = KEY(x);
    bool sel = tie ? (u > T) : (u >= T);
    smp[i + 2] = sel ? 1.f / (1.f + __expf(-fmaf(x, sc, sh))) : 0.f;
  }
  if (t < 2) smp[t] = 0.f;
  if (t < 4) smp[NL + t] = 0.f;  // covers smp[2048..2051] for v4f reads
  __syncthreads();
  if (tie && t == 0) {  // rare: stable lowest-index-first like lax.top_k
    int taken = 0;
    for (int i = 0; i < LP && taken < need_eq; ++i) {
      float x = xs[i];
      if (KEY(x) == T) {
        smp[i + 2] = 1.f / (1.f + __expf(-fmaf(x, sc, sh)));
        ++taken;
      }
    }
  }
  __syncthreads();

  // 3-tap box sum, v4f output (in-register shifts from two aligned LDS v4f)
  const float cw = comb_w[h] * (1.0f / (float)KW);
  float* row = xi + (size_t)bh * NL;
#pragma unroll
  for (int q = 0; q < 2; ++q) {
    const int l = q * 1024 + t * 4;
    v4f a = *(const v4f*)&smp[l];
    v4f bsh = *(const v4f*)&smp[l + 4];
    v4f u1 = {a.y, a.z, a.w, bsh.x};
    v4f u2 = {a.z, a.w, bsh.x, bsh.y};
    v4f r = (a + u1 + u2);
    r.x *= cw; r.y *= cw; r.z *= cw; r.w *= cw;
    *(v4f*)&row[l] = r;
  }
#undef KEY
#undef RADIX_SCAN
}

// Kernel 3 (R18-verbatim): each thread owns one (b,l4) pair, computes the
// 8-head gate sum once, reuses it across 16 channels of coalesced
// src-load + plain store. ~45us, near the 272MB mixed-stream ceiling.
__global__ __launch_bounds__(256) void scale_gate(
    const float* __restrict__ src, const float* __restrict__ xi,
    const float* __restrict__ comb_b, float* __restrict__ out) {
  const int t = threadIdx.x;
  const int cchunk = blockIdx.x >> 7;               // 0..15, 16 channels each
  const int pairidx = (blockIdx.x & 127) * 256 + t; // 0..32767
  const int b = pairidx >> 9;                       // NL/4 = 512 l4 per b
  const int l4 = pairidx & 511;
  const float cb = comb_b[0];

  const v4f* xp = (const v4f*)(xi + (size_t)b * NH * NL) + l4;
  v4f g = xp[0];
#pragma unroll
  for (int h = 1; h < NH; ++h) g += xp[(size_t)h * (NL / 4)];

  const int c0 = cchunk * (NC / 16);
  const v4f* sp = (const v4f*)src + ((size_t)b * NC + c0) * (NL / 4) + l4;
  v4f* op = (v4f*)out + ((size_t)b * NC + c0) * (NL / 4) + l4;
#pragma unroll 4
  for (int c = 0; c < NC / 16; ++c) {
    v4f sv = sp[(size_t)c * (NL / 4)];
    v4f ov;
    ov.x = fmaf(sv.x, g.x, cb);
    ov.y = fmaf(sv.y, g.y, cb);
    ov.z = fmaf(sv.z, g.z, cb);
    ov.w = fmaf(sv.w, g.w, cb);
    op[(size_t)c * (NL / 4)] = ov;
  }
}

extern "C" void kernel_launch(void* const* d_in, const int* in_sizes, int n_in,
                              void* d_out, int out_size, void* d_ws, size_t ws_size,
                              hipStream_t stream) {
  const float* src = (const float*)d_in[0];
  const float* conv_w = (const float*)d_in[1];
  const float* conv_b = (const float*)d_in[2];
  const float* bn_gamma = (const float*)d_in[3];
  const float* bn_beta = (const float*)d_in[4];
  const float* comb_w = (const float*)d_in[5];
  const float* comb_b = (const float*)d_in[6];
  const int* kptr = (const int*)d_in[7];
  float* out = (float*)d_out;

  float* xi = (float*)d_ws;  // NB*NH*NL floats (4 MB)
  float* part = out;         // 16 MB scratch inside d_out: consumed by
                             // select_block, then overwritten by scale_gate

  conv_partial<<<dim3(2, NB, NCHUNK), 512, 0, stream>>>(src, conv_w, part);
  select_block<<<NB * NH, 256, 0, stream>>>(part, xi, conv_b, bn_gamma,
                                            bn_beta, comb_w, kptr);
  scale_gate<<<2048, 256, 0, stream>>>(src, xi, comb_b, out);
}

// Round 23
// 92.026 us; speedup vs baseline: 1.1513x; 1.1112x over previous
//
#include <hip/hip_runtime.h>
#include <hip/hip_bf16.h>

#define NB 64
#define NC 256
#define NL 2048
#define NH 8
#define KW 3
#define LP (NL - KW + 1)  // 2046
#define NCHUNK 8
#define CPC (NC / NCHUNK)  // 32 channels per chunk

typedef float v4f __attribute__((ext_vector_type(4)));

// monotonic float->uint key: order(u) == order(x)
__device__ __forceinline__ unsigned fkey(float x) {
  unsigned b = __float_as_uint(x);
  return (b & 0x80000000u) ? ~b : (b | 0x80000000u);
}

// Kernel 1 (R8-proven, verbatim): conv1d partial sums. ~27us steady-state
// (measured R15 via double-launch), near its 134MB+32MB traffic floor.
__global__ __launch_bounds__(256) void conv_partial(
    const float* __restrict__ src, const float* __restrict__ conv_w,
    float* __restrict__ part) {
  const int t = threadIdx.x;
  const int lane = t & 63;
  const int l0 = blockIdx.x * 1024 + t * 4;
  const int b = blockIdx.y;
  const int cc = blockIdx.z;
  const int c0 = cc * CPC;

  float acc[NH][4];
#pragma unroll
  for (int h = 0; h < NH; ++h)
#pragma unroll
    for (int j = 0; j < 4; ++j) acc[h][j] = 0.f;

  const float* sp = src + ((size_t)b * NC + c0) * NL + l0;
  const bool tail = (lane == 63) && (l0 + 5 < NL);
#pragma unroll 2
  for (int c = 0; c < CPC; ++c) {
    v4f v = *(const v4f*)sp;
    float e0 = 0.f, e1 = 0.f;
    if (tail) { e0 = sp[4]; e1 = sp[5]; }
    sp += NL;
    float n0 = __shfl_down(v.x, 1);
    float n1 = __shfl_down(v.y, 1);
    if (lane == 63) { n0 = e0; n1 = e1; }
    float s0 = v.x, s1 = v.y, s2 = v.z, s3 = v.w, s4 = n0, s5 = n1;
#pragma unroll
    for (int h = 0; h < NH; ++h) {
      const float* w = conv_w + (h * NC + c0 + c) * KW;  // uniform -> s_load
      const float w0 = w[0], w1 = w[1], w2 = w[2];
      acc[h][0] = fmaf(s0, w0, fmaf(s1, w1, fmaf(s2, w2, acc[h][0])));
      acc[h][1] = fmaf(s1, w0, fmaf(s2, w1, fmaf(s3, w2, acc[h][1])));
      acc[h][2] = fmaf(s2, w0, fmaf(s3, w1, fmaf(s4, w2, acc[h][2])));
      acc[h][3] = fmaf(s3, w0, fmaf(s4, w1, fmaf(s5, w2, acc[h][3])));
    }
  }
#pragma unroll
  for (int h = 0; h < NH; ++h) {
    float* pr = part + ((size_t)(b * NH + h) * NCHUNK + cc) * NL + l0;
    if (l0 + 3 < LP) {
      *(v4f*)pr = *(v4f*)acc[h];
    } else {
#pragma unroll
      for (int j = 0; j < 4; ++j)
        if (l0 + j < LP) pr[j] = acc[h][j];
    }
  }
}

// Kernel 2 (R18: RAW-KEY radix — BN never materialized). BN is monotone
// affine (sign(sc)=sign(gamma), known at entry), so rank order in raw space
// equals rank order in normalized space (key-flipped if gamma<0). Phase A
// fuses load + stats + raw-key histogram into ONE sweep; pass 0's dedicated
// normalize+histogram sweep is deleted; BN applies only inside the sigmoid.
__global__ __launch_bounds__(256) void select_block(
    const float* __restrict__ part, float* __restrict__ xi,
    const float* __restrict__ conv_b, const float* __restrict__ bn_gamma,
    const float* __restrict__ bn_beta, const float* __restrict__ comb_w,
    const int* __restrict__ kptr) {
  const int t = threadIdx.x;
  const int lane = t & 63, wid = t >> 6;
  const int bh = blockIdx.x;
  const int h = bh & (NH - 1);
  __shared__ __align__(16) float xs[NL];       // raw values (pad tail unused)
  __shared__ __align__(16) float smp[NL + 4];  // doubles as cand[] in radix
  __shared__ int hist[256];
  __shared__ float rs[8];
  __shared__ float fbc[2];
  __shared__ int ibc[4];
  __shared__ int cnt;
  float* cand = smp;

  const float gma = bn_gamma[h];
  const unsigned kxor = (gma < 0.f) ? 0xFFFFFFFFu : 0u;  // key flip for sc<0
#define KEY(x) (fkey(x) ^ kxor)

  hist[t] = 0;
  __syncthreads();  // all histogram slots zeroed before any atomics

  // phase A: ONE sweep = v4f 8-stream sum (+bias) -> xs, raw stats,
  // raw-key top-byte histogram.
  const float cb = conv_b[h];
  const v4f* p0v = (const v4f*)(part + (size_t)bh * NCHUNK * NL);
  const v4f cbv = {cb, cb, cb, cb};
  float s1 = 0.f, s2 = 0.f;
#pragma unroll
  for (int half = 0; half < 2; ++half) {
    const int i0 = half * 1024 + t * 4;  // 0..2044, %4==0
    const int j = i0 >> 2;
    v4f a0 = p0v[j]        + p0v[j + 512];
    v4f a1 = p0v[j + 1024] + p0v[j + 1536];
    v4f a2 = p0v[j + 2048] + p0v[j + 2560];
    v4f a3 = p0v[j + 3072] + p0v[j + 3584];
    v4f v = ((a0 + a1) + (a2 + a3)) + cbv;
    *(v4f*)&xs[i0] = v;  // elements >= LP never read by keyed sweeps
    if (i0 + 3 < LP) {
      s1 += (v.x + v.y) + (v.z + v.w);
      s2 += (v.x * v.x + v.y * v.y) + (v.z * v.z + v.w * v.w);
      atomicAdd(&hist[KEY(v.x) >> 24], 1);
      atomicAdd(&hist[KEY(v.y) >> 24], 1);
      atomicAdd(&hist[KEY(v.z) >> 24], 1);
      atomicAdd(&hist[KEY(v.w) >> 24], 1);
    } else {  // i0 == 2044: only 2044,2045 are real
      s1 += v.x + v.y;
      s2 += v.x * v.x + v.y * v.y;
      atomicAdd(&hist[KEY(v.x) >> 24], 1);
      atomicAdd(&hist[KEY(v.y) >> 24], 1);
    }
  }
#pragma unroll
  for (int off = 32; off > 0; off >>= 1) {
    s1 += __shfl_down(s1, off);
    s2 += __shfl_down(s2, off);
  }
  if (lane == 0) { rs[wid] = s1; rs[wid + 4] = s2; }
  __syncthreads();  // hist + rs complete

  int kk = kptr[0];
#define RADIX_SCAN()                                                          \
  if (t < 64) {                                                               \
    const int h0 = hist[t * 4 + 0], h1 = hist[t * 4 + 1];                     \
    const int h2 = hist[t * 4 + 2], h3 = hist[t * 4 + 3];                     \
    const int g = h0 + h1 + h2 + h3;                                          \
    int sfx = g;                                                              \
    _Pragma("unroll")                                                         \
    for (int off = 1; off < 64; off <<= 1) {                                  \
      int o = __shfl(sfx, (t + off) & 63);                                    \
      if (t + off < 64) sfx += o;                                             \
    }                                                                         \
    const int A = sfx - g;                                                    \
    const int q3 = A + h3, q2 = q3 + h2, q1 = q2 + h1, q0 = q1 + h0;          \
    int mybin = -1, mykk = 0, myct = 0;                                       \
    if (q0 >= kk && q0 - h0 < kk) { mybin = t * 4 + 0; mykk = kk - (q0 - h0); myct = h0; } \
    if (q1 >= kk && q1 - h1 < kk) { mybin = t * 4 + 1; mykk = kk - (q1 - h1); myct = h1; } \
    if (q2 >= kk && q2 - h2 < kk) { mybin = t * 4 + 2; mykk = kk - (q2 - h2); myct = h2; } \
    if (q3 >= kk && q3 - h3 < kk) { mybin = t * 4 + 3; mykk = kk - (q3 - h3); myct = h3; } \
    if (mybin >= 0) { ibc[0] = mybin; ibc[1] = mykk; ibc[3] = myct; }         \
  }

  // stats finalize + pass-0 radix scan share one barrier section
  if (t == 0) {
    float S = rs[0] + rs[1] + rs[2] + rs[3];
    float Q = rs[4] + rs[5] + rs[6] + rs[7];
    float mu = S / (float)LP;
    float var = Q / (float)LP - mu * mu;
    float inv = rsqrtf(var + 1e-5f);
    float sc = gma * inv;
    fbc[0] = sc;
    fbc[1] = bn_beta[h] - mu * sc;
    cnt = 0;
  }
  RADIX_SCAN();
  __syncthreads();  // ibc, fbc, cnt ready

  unsigned prefix = ((unsigned)ibc[0]) << 24;
  unsigned pm = 0xFF000000u;
  kk = ibc[1];
  const unsigned b0 = (unsigned)ibc[0];

  // compact the selected top-byte bin into cand[] (order-independent result)
  for (int i = t; i < LP; i += 256) {
    float x = xs[i];
    if ((KEY(x) >> 24) == b0) {
      int p = atomicAdd(&cnt, 1);
      cand[p] = x;
    }
  }
  __syncthreads();
  const int n1 = cnt;

  // passes 1..3 over the small candidate list (raw keys)
  for (int pass = 1; pass < 4; ++pass) {
    const int shift = 24 - 8 * pass;
    hist[t] = 0;
    __syncthreads();
    for (int i = t; i < n1; i += 256) {
      unsigned u = KEY(cand[i]);
      if ((u & pm) == prefix) atomicAdd(&hist[(u >> shift) & 255], 1);
    }
    __syncthreads();
    RADIX_SCAN();
    __syncthreads();
    prefix |= ((unsigned)ibc[0]) << shift;
    pm |= 255u << shift;
    kk = ibc[1];
  }
  const unsigned T = prefix;
  const int need_eq = kk;      // # needed among keys == T (derived)
  const int ceq = ibc[3];      // # keys == T (final-pass bin count)
  const bool tie = (ceq != need_eq);

  // mask + BN + sigmoid -> smp (fully overwrites the cand alias)
  const float sc = fbc[0], sh = fbc[1];
  for (int i = t; i < LP; i += 256) {
    float x = xs[i];
    unsigned u = KEY(x);
    bool sel = tie ? (u > T) : (u >= T);
    smp[i + 2] = sel ? 1.f / (1.f + __expf(-fmaf(x, sc, sh))) : 0.f;
  }
  if (t < 2) smp[t] = 0.f;
  if (t < 4) smp[NL + t] = 0.f;  // covers smp[2048..2051] for v4f reads
  __syncthreads();
  if (tie && t == 0) {  // rare: stable lowest-index-first like lax.top_k
    int taken = 0;
    for (int i = 0; i < LP && taken < need_eq; ++i) {
      float x = xs[i];
      if (KEY(x) == T) {
        smp[i + 2] = 1.f / (1.f + __expf(-fmaf(x, sc, sh)));
        ++taken;
      }
    }
  }
  __syncthreads();

  // 3-tap box sum, v4f output (in-register shifts from two aligned LDS v4f)
  const float cw = comb_w[h] * (1.0f / (float)KW);
  float* row = xi + (size_t)bh * NL;
#pragma unroll
  for (int q = 0; q < 2; ++q) {
    const int l = q * 1024 + t * 4;
    v4f a = *(const v4f*)&smp[l];
    v4f bsh = *(const v4f*)&smp[l + 4];
    v4f u1 = {a.y, a.z, a.w, bsh.x};
    v4f u2 = {a.z, a.w, bsh.x, bsh.y};
    v4f r = (a + u1 + u2);
    r.x *= cw; r.y *= cw; r.z *= cw; r.w *= cw;
    *(v4f*)&row[l] = r;
  }
#undef KEY
#undef RADIX_SCAN
}

// Kernel 3 (R17/R18-verbatim): each thread owns one (b,l4) pair, computes
// the 8-head gate sum once, reuses it across 16 channels of coalesced
// src-load + plain store. ~45us, near the 272MB mixed-stream HBM ceiling.
__global__ __launch_bounds__(256) void scale_gate(
    const float* __restrict__ src, const float* __restrict__ xi,
    const float* __restrict__ comb_b, float* __restrict__ out) {
  const int t = threadIdx.x;
  const int cchunk = blockIdx.x >> 7;               // 0..15, 16 channels each
  const int pairidx = (blockIdx.x & 127) * 256 + t; // 0..32767
  const int b = pairidx >> 9;                       // NL/4 = 512 l4 per b
  const int l4 = pairidx & 511;
  const float cb = comb_b[0];

  const v4f* xp = (const v4f*)(xi + (size_t)b * NH * NL) + l4;
  v4f g = xp[0];
#pragma unroll
  for (int h = 1; h < NH; ++h) g += xp[(size_t)h * (NL / 4)];

  const int c0 = cchunk * (NC / 16);
  const v4f* sp = (const v4f*)src + ((size_t)b * NC + c0) * (NL / 4) + l4;
  v4f* op = (v4f*)out + ((size_t)b * NC + c0) * (NL / 4) + l4;
#pragma unroll 4
  for (int c = 0; c < NC / 16; ++c) {
    v4f sv = sp[(size_t)c * (NL / 4)];
    v4f ov;
    ov.x = fmaf(sv.x, g.x, cb);
    ov.y = fmaf(sv.y, g.y, cb);
    ov.z = fmaf(sv.z, g.z, cb);
    ov.w = fmaf(sv.w, g.w, cb);
    op[(size_t)c * (NL / 4)] = ov;
  }
}

extern "C" void kernel_launch(void* const* d_in, const int* in_sizes, int n_in,
                              void* d_out, int out_size, void* d_ws, size_t ws_size,
                              hipStream_t stream) {
  const float* src = (const float*)d_in[0];
  const float* conv_w = (const float*)d_in[1];
  const float* conv_b = (const float*)d_in[2];
  const float* bn_gamma = (const float*)d_in[3];
  const float* bn_beta = (const float*)d_in[4];
  const float* comb_w = (const float*)d_in[5];
  const float* comb_b = (const float*)d_in[6];
  const int* kptr = (const int*)d_in[7];
  float* out = (float*)d_out;

  float* xi = (float*)d_ws;  // NB*NH*NL floats (4 MB)
  float* part = out;         // 32 MB scratch inside d_out: consumed by
                             // select_block, then overwritten by scale_gate

  conv_partial<<<dim3(2, NB, NCHUNK), 256, 0, stream>>>(src, conv_w, part);
  select_block<<<NB * NH, 256, 0, stream>>>(part, xi, conv_b, bn_gamma,
                                            bn_beta, comb_w, kptr);
  scale_gate<<<2048, 256, 0, stream>>>(src, xi, comb_b, out);
}